// Round 1
// baseline (407.429 us; speedup 1.0000x reference)
//
#include <hip/hip_runtime.h>

typedef unsigned long long u64;
typedef unsigned int u32;

#define NPROP 900
#define KLVL 300
#define MAXPROP 500
#define DDIM 213
#define EDIM 208

// anchors_px / stride (all exact in binary: /8,/16,/32)
__constant__ float c_anc[3][4][2] = {
  {{1.0f, 3.0f}, {1.375f, 4.25f}, {2.0f, 6.0f}, {2.875f, 8.5f}},
  {{2.0f, 6.0f}, {2.8125f, 8.4375f}, {4.0f, 12.0f}, {5.625f, 16.9375f}},
  {{4.0f, 12.0f}, {5.625f, 16.875f}, {8.0f, 20.0f}, {16.0f, 20.0f}},
};
// stride / 608.0, double-rounded like python-float -> f32 (matches XLA weak-type promotion)
__constant__ float c_scale[3] = { (float)(8.0 / 608.0), (float)(16.0 / 608.0), (float)(32.0 / 608.0) };

__device__ __forceinline__ int level_H(int lvl) { return (lvl == 0) ? 76 : ((lvl == 1) ? 38 : 19); }

// ---------------------------------------------------------------------------
// Kernel 1: per-(image,level) conf + threshold + exact top-300 selection
// grid = 48 (b*3+lvl), block = 1024
// ---------------------------------------------------------------------------
#define TK_T 1024
__global__ __launch_bounds__(TK_T) void topk_kernel(
    const float* __restrict__ pred0, const float* __restrict__ pred1, const float* __restrict__ pred2,
    float* __restrict__ sel_score, int* __restrict__ sel_idx)
{
  __shared__ float s_sc[23104];
  __shared__ u32 s_hist[4096];
  __shared__ u32 s_scan[TK_T];
  __shared__ u32 s_sel[4];   // [0]=selected bucket [1]=K' [2]=npos

  const int lvl = blockIdx.x % 3;
  const int b = blockIdx.x / 3;
  const int t = threadIdx.x;
  const int H = level_H(lvl);
  const int HW = H * H;
  const int N = 4 * HW;
  const float* pred = (lvl == 0) ? pred0 : ((lvl == 1) ? pred1 : pred2);
  const float* pb = pred + (size_t)b * N * 6;

  if (t == 0) s_sel[2] = 0;
  u32 nploc = 0;
  for (int n = t; n < N; n += TK_T) {
    // softmax over 2 logits, max-subtracted exactly like jax.nn.softmax
    float2 l = *reinterpret_cast<const float2*>(pb + (size_t)n * 6 + 4);
    float m = fmaxf(l.x, l.y);
    float e0 = expf(l.x - m), e1 = expf(l.y - m);
    float s = e1 / (e0 + e1);
    float sm = (s > 0.5f) ? s : 0.0f;
    s_sc[n] = sm;
    if (sm > 0.0f) nploc++;
  }
  __syncthreads();
  if (nploc) atomicAdd(&s_sel[2], nploc);
  __syncthreads();
  const u32 Npos = s_sel[2];
  const bool take_all = (Npos <= (u32)KLVL);
  u32 K = KLVL;
  u32 prefHi = 0, Tkey = 0;

  if (!take_all) {
    // 2-pass radix select over key = float_bits - 0x3F000000 (conf in (0.5, 1])
    for (int pass = 0; pass < 2; ++pass) {
      for (int i = t; i < 4096; i += TK_T) s_hist[i] = 0;
      __syncthreads();
      for (int n = t; n < N; n += TK_T) {
        float v = s_sc[n];
        if (v <= 0.0f) continue;
        u32 key = __float_as_uint(v) - 0x3F000000u;
        if (pass == 0) atomicAdd(&s_hist[key >> 12], 1u);
        else if ((key >> 12) == prefHi) atomicAdd(&s_hist[key & 0xFFFu], 1u);
      }
      __syncthreads();
      const int b0 = t * 4;
      u32 partial = s_hist[b0] + s_hist[b0 + 1] + s_hist[b0 + 2] + s_hist[b0 + 3];
      s_scan[t] = partial;
      __syncthreads();
      // suffix (from-top) inclusive scan of the 1024 partials
      for (int off = 1; off < TK_T; off <<= 1) {
        u32 x = s_scan[t];
        u32 add = (t + off < TK_T) ? s_scan[t + off] : 0u;
        __syncthreads();
        s_scan[t] = x + add;
        __syncthreads();
      }
      u32 running = (t + 1 < TK_T) ? s_scan[t + 1] : 0u;
      for (int i = 3; i >= 0; --i) {
        u32 h = s_hist[b0 + i];
        if (h && running < K && K <= running + h) { s_sel[0] = (u32)(b0 + i); s_sel[1] = K - running; }
        running += h;
      }
      __syncthreads();
      if (pass == 0) prefHi = s_sel[0];
      else Tkey = (prefHi << 12) | s_sel[0];
      K = s_sel[1];
      __syncthreads();
    }
  }
  const u32 need_ties = take_all ? 0u : K;            // # of ==T elements to take (lowest idx first)
  const u32 G = take_all ? Npos : ((u32)KLVL - need_ties); // # strictly greater than T
  const u32 Tbits = Tkey + 0x3F000000u;

  // deterministic ordered compaction: contiguous chunk per thread + exclusive scans
  const int chunk = (N + TK_T - 1) / TK_T;
  const int lo = t * chunk;
  const int hi = (lo + chunk < N) ? (lo + chunk) : N;
  u32 cg = 0, ct = 0;
  for (int n = lo; n < hi; ++n) {
    float v = s_sc[n];
    if (v <= 0.0f) continue;
    u32 bits = __float_as_uint(v);
    if (take_all || bits > Tbits) cg++;
    else if (bits == Tbits) ct++;
  }
  s_scan[t] = cg;
  __syncthreads();
  for (int off = 1; off < TK_T; off <<= 1) {
    u32 x = s_scan[t];
    u32 add = (t >= off) ? s_scan[t - off] : 0u;
    __syncthreads();
    s_scan[t] = x + add;
    __syncthreads();
  }
  u32 g_pos = s_scan[t] - cg;
  __syncthreads();
  s_scan[t] = ct;
  __syncthreads();
  for (int off = 1; off < TK_T; off <<= 1) {
    u32 x = s_scan[t];
    u32 add = (t >= off) ? s_scan[t - off] : 0u;
    __syncthreads();
    s_scan[t] = x + add;
    __syncthreads();
  }
  u32 t_pos = s_scan[t] - ct;

  float* out_s = sel_score + (size_t)b * NPROP + (size_t)lvl * KLVL;
  int* out_i = sel_idx + (size_t)b * NPROP + (size_t)lvl * KLVL;
  for (int n = lo; n < hi; ++n) {
    float v = s_sc[n];
    if (v <= 0.0f) continue;
    u32 bits = __float_as_uint(v);
    if (take_all || bits > Tbits) {
      out_s[g_pos] = v; out_i[g_pos] = n; g_pos++;
    } else if (bits == Tbits) {
      if (t_pos < need_ties) { out_s[G + t_pos] = v; out_i[G + t_pos] = n; }
      t_pos++;
    }
  }
  const u32 total = take_all ? Npos : (u32)KLVL;
  for (u32 s2 = total + (u32)t; s2 < (u32)KLVL; s2 += TK_T) { out_s[s2] = 0.0f; out_i[s2] = 0; }
}

// ---------------------------------------------------------------------------
// Kernel 2: per-image sort + greedy NMS + decode/gather output
// grid = 16, block = 1024
// ---------------------------------------------------------------------------
#define NM_T 1024
__global__ __launch_bounds__(NM_T) void nms_kernel(
    const float* __restrict__ pred0, const float* __restrict__ pred1, const float* __restrict__ pred2,
    const float* __restrict__ emb0, const float* __restrict__ emb1, const float* __restrict__ emb2,
    const float* __restrict__ sel_score, const int* __restrict__ sel_idx,
    float* __restrict__ out)
{
  __shared__ u64 s_key[1024];
  __shared__ float s_x1[NPROP], s_y1[NPROP], s_x2[NPROP], s_y2[NPROP], s_ar[NPROP];
  __shared__ u64 s_mask[NPROP * 15];
  __shared__ u64 s_keepw[16];
  __shared__ u32 s_wpre[16];
  __shared__ int s_src[MAXPROP];
  __shared__ u32 s_np;

  const int b = blockIdx.x;
  const int t = threadIdx.x;
  const float* selS = sel_score + (size_t)b * NPROP;
  const int* selI = sel_idx + (size_t)b * NPROP;

  // key = score_bits : (~slot)  -> descending sort == (score desc, slot asc) == stable argsort(-sc)
  {
    u64 key = 0;
    if (t < NPROP) {
      float v = selS[t];
      key = ((u64)__float_as_uint(v) << 32) | (u64)(0xFFFFFFFFu - (u32)t);
    }
    s_key[t] = key;
  }
  if (t == 0) s_np = 0;
  __syncthreads();

  // bitonic sort, descending, 1024 keys
  for (u32 k = 2; k <= 1024; k <<= 1) {
    for (u32 j = k >> 1; j > 0; j >>= 1) {
      u32 i = (u32)t;
      u32 ixj = i ^ j;
      if (ixj > i) {
        u64 a = s_key[i], c = s_key[ixj];
        bool sw = ((i & k) == 0) ? (a < c) : (a > c);
        if (sw) { s_key[i] = c; s_key[ixj] = a; }
      }
      __syncthreads();
    }
  }

  if ((u32)(s_key[t] >> 32) != 0u) atomicAdd(&s_np, 1u);
  __syncthreads();
  const int Np = (int)s_np;            // count of positive-score candidates (sorted first)
  const int nW = (Np + 63) >> 6;

  // decode boxes for the Np live candidates, in sorted order
  for (int i = t; i < Np; i += NM_T) {
    u64 key = s_key[i];
    int slot = (int)(0xFFFFFFFFu - (u32)(key & 0xFFFFFFFFull));
    int lvl = slot / KLVL;
    int n = selI[slot];
    int Hl = level_H(lvl);
    int HWl = Hl * Hl;
    int a = n / HWl; int rem = n - a * HWl;
    int gy = rem / Hl; int gx = rem - gy * Hl;
    const float* pred = (lvl == 0) ? pred0 : ((lvl == 1) ? pred1 : pred2);
    const float* p = pred + ((size_t)b * 4 * HWl + (size_t)n) * 6;
    float p0 = p[0], p1 = p[1], p2 = p[2], p3 = p[3];
    float aw = c_anc[lvl][a][0], ah = c_anc[lvl][a][1];
    float x = p0 * aw + (float)gx;
    float y = p1 * ah + (float)gy;
    float wv = expf(p2) * aw;
    float hv = expf(p3) * ah;
    float sc = c_scale[lvl];
    float x1 = fminf(fmaxf((x - 0.5f * wv) * sc, 0.0f), 1.0f);
    float y1 = fminf(fmaxf((y - 0.5f * hv) * sc, 0.0f), 1.0f);
    float x2 = fminf(fmaxf((x + 0.5f * wv) * sc, 0.0f), 1.0f);
    float y2 = fminf(fmaxf((y + 0.5f * hv) * sc, 0.0f), 1.0f);
    s_x1[i] = x1; s_y1[i] = y1; s_x2[i] = x2; s_y2[i] = y2;
    s_ar[i] = (x2 - x1) * (y2 - y1);
  }
  __syncthreads();

  // suppression bitmask: bit (i, j>i) set iff iou > 0.45
  for (int task = t; task < nW * Np; task += NM_T) {
    int w = task / Np;
    int i = task - w * Np;
    int j0 = w << 6;
    u64 bits = 0;
    if (j0 + 63 > i) {
      float xi1 = s_x1[i], yi1 = s_y1[i], xi2 = s_x2[i], yi2 = s_y2[i], ai = s_ar[i];
      for (int jj = 0; jj < 64; ++jj) {
        int j = j0 + jj;
        if (j > i && j < Np) {
          float xx1 = fmaxf(xi1, s_x1[j]);
          float yy1 = fmaxf(yi1, s_y1[j]);
          float xx2 = fminf(xi2, s_x2[j]);
          float yy2 = fminf(yi2, s_y2[j]);
          float iw = fmaxf(xx2 - xx1, 0.0f);
          float ih = fmaxf(yy2 - yy1, 0.0f);
          float inter = iw * ih;
          float iou = inter / (ai + s_ar[j] - inter + 1e-9f);
          if (iou > 0.45f) bits |= (1ull << jj);
        }
      }
    }
    s_mask[i * 15 + w] = bits;
  }
  __syncthreads();

  // serial greedy scan, 15-lane distributed removal set (wave 0)
  if (t < 64) {
    const int w = t;
    u64 remv = 0;
    for (int i = 0; i < Np; ++i) {
      u32 mybit = (u32)((remv >> (i & 63)) & 1ull);
      u32 sup = (u32)__shfl((int)mybit, i >> 6, 64);
      u64 mrow = (w < nW) ? s_mask[i * 15 + w] : 0ull;
      if (!sup) remv |= mrow;
    }
    if (w < 15) {
      int base = w << 6;
      u64 valid = 0;
      if (Np > base) {
        int r = Np - base;
        valid = (r >= 64) ? ~0ull : ((1ull << r) - 1ull);
      }
      s_keepw[w] = (~remv) & valid;
    }
  }
  __syncthreads();

  if (t == 0) {
    u32 run = 0;
    for (int w = 0; w < 15; ++w) { s_wpre[w] = run; run += (u32)__popcll(s_keepw[w]); }
  }
  for (int r = t; r < MAXPROP; r += NM_T) s_src[r] = -1;
  __syncthreads();

  for (int i = t; i < Np; i += NM_T) {
    u64 kw = s_keepw[i >> 6];
    if ((kw >> (i & 63)) & 1ull) {
      u32 rank = s_wpre[i >> 6] + (u32)__popcll(kw & ((1ull << (i & 63)) - 1ull));
      if (rank < MAXPROP) s_src[rank] = i;
    }
  }
  __syncthreads();

  // output: one wave per row; gather+normalize emb only for kept rows
  float* ob = out + (size_t)b * MAXPROP * DDIM;
  const int wv_ = t >> 6, lane = t & 63;
  for (int r = wv_; r < MAXPROP; r += 16) {
    float* orow = ob + (size_t)r * DDIM;
    int i = s_src[r];
    if (i < 0) {
      for (int c = lane; c < DDIM; c += 64) orow[c] = 0.0f;
      continue;
    }
    u64 key = s_key[i];
    int slot = (int)(0xFFFFFFFFu - (u32)(key & 0xFFFFFFFFull));
    float score = __uint_as_float((u32)(key >> 32));
    int lvl = slot / KLVL;
    int n = selI[slot];
    int Hl = level_H(lvl);
    int HWl = Hl * Hl;
    int a = n / HWl; int rem = n - a * HWl;
    int gy = rem / Hl; int gx = rem - gy * Hl;
    const float* emb = (lvl == 0) ? emb0 : ((lvl == 1) ? emb1 : emb2);
    const float* e = emb + ((size_t)(b * Hl + gy) * Hl + gx) * EDIM;
    float v0 = e[lane], v1 = e[lane + 64], v2 = e[lane + 128];
    float v3 = (lane < 16) ? e[lane + 192] : 0.0f;
    float ss = v0 * v0 + v1 * v1 + v2 * v2 + v3 * v3;
    for (int off = 32; off > 0; off >>= 1) ss += __shfl_xor(ss, off, 64);
    float rs = 1.0f / sqrtf(fmaxf(ss, 1e-12f));
    if (lane == 0) {
      orow[0] = s_x1[i]; orow[1] = s_y1[i]; orow[2] = s_x2[i]; orow[3] = s_y2[i];
      orow[4] = score;
    }
    orow[5 + lane] = v0 * rs;
    orow[5 + 64 + lane] = v1 * rs;
    orow[5 + 128 + lane] = v2 * rs;
    if (lane < 16) orow[5 + 192 + lane] = v3 * rs;
  }
}

// ---------------------------------------------------------------------------
extern "C" void kernel_launch(void* const* d_in, const int* in_sizes, int n_in,
                              void* d_out, int out_size, void* d_ws, size_t ws_size,
                              hipStream_t stream) {
  // map inputs by element count (robust to ordering): pred0,emb0,pred1,emb1,pred2,emb2
  const float* pred[3] = {nullptr, nullptr, nullptr};
  const float* emb[3] = {nullptr, nullptr, nullptr};
  for (int i = 0; i < n_in; ++i) {
    const float* p = (const float*)d_in[i];
    switch (in_sizes[i]) {
      case 2217984:  pred[0] = p; break;   // 16*4*76*76*6
      case 554496:   pred[1] = p; break;   // 16*4*38*38*6
      case 138624:   pred[2] = p; break;   // 16*4*19*19*6
      case 19222528: emb[0] = p; break;    // 16*76*76*208
      case 4805632:  emb[1] = p; break;    // 16*38*38*208
      case 1201408:  emb[2] = p; break;    // 16*19*19*208
      default: break;
    }
  }
  float* sel_score = (float*)d_ws;
  int* sel_idx = (int*)((char*)d_ws + (size_t)16 * NPROP * sizeof(float));

  topk_kernel<<<dim3(48), dim3(TK_T), 0, stream>>>(pred[0], pred[1], pred[2], sel_score, sel_idx);
  nms_kernel<<<dim3(16), dim3(NM_T), 0, stream>>>(pred[0], pred[1], pred[2],
                                                  emb[0], emb[1], emb[2],
                                                  sel_score, sel_idx, (float*)d_out);
}

// Round 2
// 276.659 us; speedup vs baseline: 1.4727x; 1.4727x over previous
//
#include <hip/hip_runtime.h>

typedef unsigned long long u64;
typedef unsigned int u32;

#define KLVL 300
#define NPROP 900
#define MAXPROP 500
#define DDIM 213
#define EDIM 208

// anchors_px / stride (all exact in binary: /8,/16,/32)
__constant__ float c_anc[3][4][2] = {
  {{1.0f, 3.0f}, {1.375f, 4.25f}, {2.0f, 6.0f}, {2.875f, 8.5f}},
  {{2.0f, 6.0f}, {2.8125f, 8.4375f}, {4.0f, 12.0f}, {5.625f, 16.9375f}},
  {{4.0f, 12.0f}, {5.625f, 16.875f}, {8.0f, 20.0f}, {16.0f, 20.0f}},
};
__constant__ float c_scale[3] = { (float)(8.0 / 608.0), (float)(16.0 / 608.0), (float)(32.0 / 608.0) };

__device__ __forceinline__ int level_H(int lvl) { return (lvl == 0) ? 76 : ((lvl == 1) ? 38 : 19); }

// ---------------- workspace layout (bytes) ----------------
#define WS_SELS 0                 // 16*900 f32
#define WS_SELI (64*1024)         // 16*900 i32
#define WS_CNT  (128*1024)        // 16*3 i32
#define WS_BOX  (136*1024)        // per image: 7 arrays x 928 f32 (X1,Y1,X2,Y2,AR,SC,SLOT(int))
#define BOX_STRIDE 928
#define BOX_IMG (7*928)
#define WS_MASK (576*1024)        // per image: 904*15 u64
#define MASK_IMG (904*15)
#define WS_SRC  (2432*1024)       // 16*500 i32

// ---------------------------------------------------------------------------
// Kernel 1: per-(image,level) conf + threshold + exact top-300, sorted output
// grid = 48 (b*3+lvl), block = 1024
// ---------------------------------------------------------------------------
#define TK_T 1024
__global__ __launch_bounds__(TK_T) void topk_kernel(
    const float* __restrict__ pred0, const float* __restrict__ pred1, const float* __restrict__ pred2,
    float* __restrict__ sel_score, int* __restrict__ sel_idx, int* __restrict__ cnt)
{
  __shared__ float s_sc[23104];
  __shared__ u32 s_hist[4096];
  __shared__ u32 s_wt[16];
  __shared__ u64 s_wt64[16];
  __shared__ u32 s_sel[4];
  __shared__ float s_selS[KLVL];
  __shared__ int   s_selI[KLVL];

  const int lvl = blockIdx.x % 3;
  const int b = blockIdx.x / 3;
  const int t = threadIdx.x;
  const int lane = t & 63, wid = t >> 6;
  const int H = level_H(lvl);
  const int HW = H * H;
  const int N = 4 * HW;
  const float* pred = (lvl == 0) ? pred0 : ((lvl == 1) ? pred1 : pred2);
  const float* pb = pred + (size_t)b * N * 6;

  if (t == 0) s_sel[2] = 0;
  u32 nploc = 0;
  for (int n = t; n < N; n += TK_T) {
    float2 l = *reinterpret_cast<const float2*>(pb + (size_t)n * 6 + 4);
    float m = fmaxf(l.x, l.y);
    float e0 = expf(l.x - m), e1 = expf(l.y - m);
    float s = e1 / (e0 + e1);
    float sm = (s > 0.5f) ? s : 0.0f;
    s_sc[n] = sm;
    nploc += (sm > 0.0f) ? 1u : 0u;
  }
  __syncthreads();
  if (nploc) atomicAdd(&s_sel[2], nploc);
  __syncthreads();
  const u32 Npos = s_sel[2];
  const bool take_all = (Npos <= (u32)KLVL);
  u32 K = KLVL;
  u32 prefHi = 0, Tkey = 0;

  if (!take_all) {
    // 2-pass radix select over key = float_bits - 0x3F000000 (conf in (0.5, 1])
    for (int pass = 0; pass < 2; ++pass) {
      for (int i = t; i < 4096; i += TK_T) s_hist[i] = 0;
      __syncthreads();
      for (int n = t; n < N; n += TK_T) {
        float v = s_sc[n];
        if (v <= 0.0f) continue;
        u32 key = __float_as_uint(v) - 0x3F000000u;
        if (pass == 0) atomicAdd(&s_hist[key >> 12], 1u);
        else if ((key >> 12) == prefHi) atomicAdd(&s_hist[key & 0xFFFu], 1u);
      }
      __syncthreads();
      // thread t owns 4 buckets from the top: 4095-4t, 4095-4t-1, ...
      const int btop = 4095 - 4 * t;
      u32 h0 = s_hist[btop], h1 = s_hist[btop - 1], h2 = s_hist[btop - 2], h3 = s_hist[btop - 3];
      u32 partial = h0 + h1 + h2 + h3;
      u32 incl = partial;
      #pragma unroll
      for (int off = 1; off < 64; off <<= 1) { u32 v2 = __shfl_up(incl, (unsigned)off, 64); if (lane >= off) incl += v2; }
      if (lane == 63) s_wt[wid] = incl;
      __syncthreads();
      u32 above = 0;
      for (int w2 = 0; w2 < wid; ++w2) above += s_wt[w2];
      u32 running = above + incl - partial;  // count strictly above my 4-bucket chunk
      u32 hh0 = h0, hh1 = h1, hh2 = h2, hh3 = h3;
      if (hh0 && running < K && K <= running + hh0) { s_sel[0] = (u32)(btop);     s_sel[1] = K - running; }
      running += hh0;
      if (hh1 && running < K && K <= running + hh1) { s_sel[0] = (u32)(btop - 1); s_sel[1] = K - running; }
      running += hh1;
      if (hh2 && running < K && K <= running + hh2) { s_sel[0] = (u32)(btop - 2); s_sel[1] = K - running; }
      running += hh2;
      if (hh3 && running < K && K <= running + hh3) { s_sel[0] = (u32)(btop - 3); s_sel[1] = K - running; }
      __syncthreads();
      if (pass == 0) prefHi = s_sel[0];
      else Tkey = (prefHi << 12) | s_sel[0];
      K = s_sel[1];
      __syncthreads();
    }
  }
  const u32 need_ties = take_all ? 0u : K;
  const u32 G = take_all ? Npos : ((u32)KLVL - need_ties);
  const u32 Tbits = Tkey + 0x3F000000u;

  // deterministic ordered compaction via packed (cg,ct) wave scans
  const int chunk = (N + TK_T - 1) / TK_T;
  const int lo = t * chunk;
  const int hi = (lo + chunk < N) ? (lo + chunk) : N;
  u32 cg = 0, ct = 0;
  for (int n = lo; n < hi; ++n) {
    float v = s_sc[n];
    if (v <= 0.0f) continue;
    u32 bits = __float_as_uint(v);
    if (take_all || bits > Tbits) cg++;
    else if (bits == Tbits) ct++;
  }
  u64 pc = ((u64)cg << 32) | (u64)ct;
  u64 incl64 = pc;
  #pragma unroll
  for (int off = 1; off < 64; off <<= 1) { u64 v2 = __shfl_up(incl64, (unsigned)off, 64); if (lane >= off) incl64 += v2; }
  if (lane == 63) s_wt64[wid] = incl64;
  __syncthreads();
  u64 ab = 0;
  for (int w2 = 0; w2 < wid; ++w2) ab += s_wt64[w2];
  u64 excl = ab + incl64 - pc;
  u32 g_pos = (u32)(excl >> 32);
  u32 t_pos = (u32)excl;
  for (int n = lo; n < hi; ++n) {
    float v = s_sc[n];
    if (v <= 0.0f) continue;
    u32 bits = __float_as_uint(v);
    if (take_all || bits > Tbits) {
      s_selS[g_pos] = v; s_selI[g_pos] = n; g_pos++;
    } else if (bits == Tbits) {
      if (t_pos < need_ties) { s_selS[G + t_pos] = v; s_selI[G + t_pos] = n; }
      t_pos++;
    }
  }
  __syncthreads();

  // rank the <=300 selected by (score desc, idx asc) -> write sorted (== lax.top_k order)
  const u32 total = take_all ? Npos : (u32)KLVL;
  float* out_s = sel_score + (size_t)b * NPROP + (size_t)lvl * KLVL;
  int* out_i = sel_idx + (size_t)b * NPROP + (size_t)lvl * KLVL;
  if ((u32)t < total) {
    float sv = s_selS[t]; int iv = s_selI[t];
    u32 r = 0;
    for (u32 j = 0; j < total; ++j) {
      float sj = s_selS[j]; int ij = s_selI[j];
      r += ((sj > sv) || (sj == sv && ij < iv)) ? 1u : 0u;
    }
    out_s[r] = sv; out_i[r] = iv;
  }
  if (t == 0) cnt[b * 3 + lvl] = (int)total;
}

// ---------------------------------------------------------------------------
// Kernel 2: global rank (3-way sorted merge via binary search) + box decode
// grid = 16, block = 1024
// ---------------------------------------------------------------------------
__global__ __launch_bounds__(1024) void rank_kernel(
    const float* __restrict__ pred0, const float* __restrict__ pred1, const float* __restrict__ pred2,
    const float* __restrict__ sel_score, const int* __restrict__ sel_idx, const int* __restrict__ cnt,
    float* __restrict__ ws_box)
{
  __shared__ float s_sc[NPROP];
  __shared__ int s_ix[NPROP];
  __shared__ int s_c[3];
  const int b = blockIdx.x, t = threadIdx.x;
  if (t < 3) s_c[t] = cnt[b * 3 + t];
  if (t < NPROP) { s_sc[t] = sel_score[(size_t)b * NPROP + t]; s_ix[t] = sel_idx[(size_t)b * NPROP + t]; }
  __syncthreads();
  if (t < NPROP) {
    int lvl = t / KLVL, pos = t - lvl * KLVL;
    if (pos < s_c[lvl]) {
      float sv = s_sc[t];
      u32 rank = (u32)pos;
      for (int ol = 0; ol < 3; ++ol) {
        if (ol == lvl) continue;
        int base = ol * KLVL, co = s_c[ol];
        int lo2 = 0, hi2 = co;
        if (ol < lvl) {  // earlier level: equal score ranks before me (count >=)
          while (lo2 < hi2) { int mid = (lo2 + hi2) >> 1; if (s_sc[base + mid] >= sv) lo2 = mid + 1; else hi2 = mid; }
        } else {         // later level: only strictly greater
          while (lo2 < hi2) { int mid = (lo2 + hi2) >> 1; if (s_sc[base + mid] > sv) lo2 = mid + 1; else hi2 = mid; }
        }
        rank += (u32)lo2;
      }
      // decode this candidate's box (identical numerics to reference path)
      int n = s_ix[t];
      int Hl = level_H(lvl), HWl = Hl * Hl;
      int a = n / HWl, rem = n - a * HWl, gy = rem / Hl, gx = rem - gy * Hl;
      const float* pred = (lvl == 0) ? pred0 : ((lvl == 1) ? pred1 : pred2);
      const float* p = pred + ((size_t)b * 4 * HWl + (size_t)n) * 6;
      float p0 = p[0], p1 = p[1], p2 = p[2], p3 = p[3];
      float aw = c_anc[lvl][a][0], ah = c_anc[lvl][a][1];
      float x = p0 * aw + (float)gx;
      float y = p1 * ah + (float)gy;
      float wv = expf(p2) * aw;
      float hv = expf(p3) * ah;
      float sc = c_scale[lvl];
      float x1 = fminf(fmaxf((x - 0.5f * wv) * sc, 0.0f), 1.0f);
      float y1 = fminf(fmaxf((y - 0.5f * hv) * sc, 0.0f), 1.0f);
      float x2 = fminf(fmaxf((x + 0.5f * wv) * sc, 0.0f), 1.0f);
      float y2 = fminf(fmaxf((y + 0.5f * hv) * sc, 0.0f), 1.0f);
      float* Bx = ws_box + (size_t)b * BOX_IMG;
      Bx[rank] = x1;
      Bx[BOX_STRIDE + rank] = y1;
      Bx[2 * BOX_STRIDE + rank] = x2;
      Bx[3 * BOX_STRIDE + rank] = y2;
      Bx[4 * BOX_STRIDE + rank] = (x2 - x1) * (y2 - y1);
      Bx[5 * BOX_STRIDE + rank] = sv;
      ((int*)(Bx + 6 * BOX_STRIDE))[rank] = t;   // slot
    }
  }
}

// ---------------------------------------------------------------------------
// Kernel 3: IoU suppression bitmask, spread over (word w, image b) blocks
// grid = (15, 16), block = 256
// ---------------------------------------------------------------------------
__global__ __launch_bounds__(256) void mask_kernel(
    const float* __restrict__ ws_box, const int* __restrict__ cnt, u64* __restrict__ ws_mask)
{
  const int w = blockIdx.x, b = blockIdx.y, t = threadIdx.x;
  const float* B = ws_box + (size_t)b * BOX_IMG;
  const float* X1 = B, * Y1 = B + BOX_STRIDE, * X2 = B + 2 * BOX_STRIDE,
             * Y2 = B + 3 * BOX_STRIDE, * AR = B + 4 * BOX_STRIDE;
  const int Np = cnt[b * 3] + cnt[b * 3 + 1] + cnt[b * 3 + 2];
  __shared__ float jx1[64], jy1[64], jx2[64], jy2[64], jar[64];
  if (t < 64) {
    int j = w * 64 + t;
    if (j < Np) { jx1[t] = X1[j]; jy1[t] = Y1[j]; jx2[t] = X2[j]; jy2[t] = Y2[j]; jar[t] = AR[j]; }
  }
  __syncthreads();
  u64* mk = ws_mask + (size_t)b * MASK_IMG;
  const int jlim = min(64, Np - w * 64);
  for (int i = t; i < Np; i += 256) {
    u64 bits = 0;
    if (i < w * 64 + 63 && jlim > 0) {
      float xi1 = X1[i], yi1 = Y1[i], xi2 = X2[i], yi2 = Y2[i], ai = AR[i];
      for (int jj = 0; jj < jlim; ++jj) {
        int j = w * 64 + jj;
        if (j > i) {
          float xx1 = fmaxf(xi1, jx1[jj]);
          float yy1 = fmaxf(yi1, jy1[jj]);
          float xx2 = fminf(xi2, jx2[jj]);
          float yy2 = fminf(yi2, jy2[jj]);
          float iw = fmaxf(xx2 - xx1, 0.0f);
          float ih = fmaxf(yy2 - yy1, 0.0f);
          float inter = iw * ih;
          float iou = inter / (ai + jar[jj] - inter + 1e-9f);
          if (iou > 0.45f) bits |= (1ull << jj);
        }
      }
    }
    mk[(size_t)i * 15 + w] = bits;
  }
}

// ---------------------------------------------------------------------------
// Kernel 4: serial greedy scan (readlane-based) + keep-rank -> src list
// grid = 16, block = 256 (scan runs on wave 0)
// ---------------------------------------------------------------------------
__global__ __launch_bounds__(256) void scan_kernel(
    const u64* __restrict__ ws_mask, const int* __restrict__ cnt, int* __restrict__ ws_src)
{
  __shared__ u64 sm[904 * 15];
  __shared__ u64 s_keep[15];
  __shared__ u32 s_pre[16];
  const int b = blockIdx.x, t = threadIdx.x;
  const int Np = cnt[b * 3] + cnt[b * 3 + 1] + cnt[b * 3 + 2];
  const u64* mk = ws_mask + (size_t)b * MASK_IMG;
  for (int i = t; i < Np * 15; i += 256) sm[i] = mk[i];
  __syncthreads();

  if (t < 64) {
    const int lane = t;
    const int lw = (lane < 15) ? lane : 0;   // clamp: lanes>=15 read valid junk, never used
    u64 remv = 0;
    u64 r0 = sm[0 * 15 + lw], r1 = sm[1 * 15 + lw], r2 = sm[2 * 15 + lw], r3 = sm[3 * 15 + lw];
    const int Np4 = Np & ~3;
#define NMS_STEP(ii, rr) { \
      u32 bit_ = (u32)(remv >> ((ii) & 63)) & 1u; \
      u32 sup_ = (u32)__builtin_amdgcn_readlane((int)bit_, (ii) >> 6); \
      if (!sup_) remv |= (rr); }
    for (int i = 0; i < Np4; i += 4) {
      u64 n0 = sm[(size_t)(i + 4) * 15 + lw];
      u64 n1 = sm[(size_t)(i + 5) * 15 + lw];
      u64 n2 = sm[(size_t)(i + 6) * 15 + lw];
      u64 n3 = sm[(size_t)(i + 7) * 15 + lw];
      NMS_STEP(i, r0);
      NMS_STEP(i + 1, r1);
      NMS_STEP(i + 2, r2);
      NMS_STEP(i + 3, r3);
      r0 = n0; r1 = n1; r2 = n2; r3 = n3;
    }
    if (Np4 + 0 < Np) NMS_STEP(Np4 + 0, r0);
    if (Np4 + 1 < Np) NMS_STEP(Np4 + 1, r1);
    if (Np4 + 2 < Np) NMS_STEP(Np4 + 2, r2);
    if (Np4 + 3 < Np) NMS_STEP(Np4 + 3, r3);
#undef NMS_STEP
    if (lane < 15) {
      int base = lane << 6;
      u64 valid = 0;
      if (Np > base) {
        int r = Np - base;
        valid = (r >= 64) ? ~0ull : ((1ull << r) - 1ull);
      }
      s_keep[lane] = (~remv) & valid;
    }
  }
  __syncthreads();
  if (t == 0) {
    u32 run = 0;
    for (int w2 = 0; w2 < 15; ++w2) { s_pre[w2] = run; run += (u32)__popcll(s_keep[w2]); }
  }
  int* src = ws_src + b * MAXPROP;
  for (int r = t; r < MAXPROP; r += 256) src[r] = -1;
  __syncthreads();
  for (int i = t; i < Np; i += 256) {
    u64 kw = s_keep[i >> 6];
    if ((kw >> (i & 63)) & 1ull) {
      u32 rank = s_pre[i >> 6] + (u32)__popcll(kw & ((1ull << (i & 63)) - 1ull));
      if (rank < MAXPROP) src[rank] = i;
    }
  }
}

// ---------------------------------------------------------------------------
// Kernel 5: output rows — one wave per row, spread over 2000 blocks
// grid = 16*125, block = 256
// ---------------------------------------------------------------------------
__global__ __launch_bounds__(256) void out_kernel(
    const float* __restrict__ emb0, const float* __restrict__ emb1, const float* __restrict__ emb2,
    const float* __restrict__ ws_box, const int* __restrict__ ws_src, const int* __restrict__ sel_idx,
    float* __restrict__ out)
{
  const int blk = blockIdx.x;
  const int b = blk / 125;
  const int r = (blk % 125) * 4 + (threadIdx.x >> 6);
  const int lane = threadIdx.x & 63;
  float* orow = out + ((size_t)b * MAXPROP + r) * DDIM;
  const int i = ws_src[b * MAXPROP + r];
  if (i < 0) {
    for (int c = lane; c < DDIM; c += 64) orow[c] = 0.0f;
    return;
  }
  const float* B = ws_box + (size_t)b * BOX_IMG;
  float x1 = B[i], y1 = B[BOX_STRIDE + i], x2 = B[2 * BOX_STRIDE + i], y2 = B[3 * BOX_STRIDE + i];
  float score = B[5 * BOX_STRIDE + i];
  int slot = ((const int*)(B + 6 * BOX_STRIDE))[i];
  int n = sel_idx[(size_t)b * NPROP + slot];
  int lvl = slot / KLVL;
  int Hl = level_H(lvl), HWl = Hl * Hl;
  int a = n / HWl, rem = n - a * HWl, gy = rem / Hl, gx = rem - gy * Hl;
  (void)a;
  const float* emb = (lvl == 0) ? emb0 : ((lvl == 1) ? emb1 : emb2);
  const float* e = emb + ((size_t)(b * Hl + gy) * Hl + gx) * EDIM;
  float v0 = e[lane], v1 = e[lane + 64], v2 = e[lane + 128];
  float v3 = (lane < 16) ? e[lane + 192] : 0.0f;
  float ss = v0 * v0 + v1 * v1 + v2 * v2 + v3 * v3;
  for (int off = 32; off > 0; off >>= 1) ss += __shfl_xor(ss, off, 64);
  float rs = 1.0f / sqrtf(fmaxf(ss, 1e-12f));
  if (lane == 0) {
    orow[0] = x1; orow[1] = y1; orow[2] = x2; orow[3] = y2; orow[4] = score;
  }
  orow[5 + lane] = v0 * rs;
  orow[5 + 64 + lane] = v1 * rs;
  orow[5 + 128 + lane] = v2 * rs;
  if (lane < 16) orow[5 + 192 + lane] = v3 * rs;
}

// ---------------------------------------------------------------------------
extern "C" void kernel_launch(void* const* d_in, const int* in_sizes, int n_in,
                              void* d_out, int out_size, void* d_ws, size_t ws_size,
                              hipStream_t stream) {
  const float* pred[3] = {nullptr, nullptr, nullptr};
  const float* emb[3] = {nullptr, nullptr, nullptr};
  for (int i = 0; i < n_in; ++i) {
    const float* p = (const float*)d_in[i];
    switch (in_sizes[i]) {
      case 2217984:  pred[0] = p; break;   // 16*4*76*76*6
      case 554496:   pred[1] = p; break;   // 16*4*38*38*6
      case 138624:   pred[2] = p; break;   // 16*4*19*19*6
      case 19222528: emb[0] = p; break;    // 16*76*76*208
      case 4805632:  emb[1] = p; break;    // 16*38*38*208
      case 1201408:  emb[2] = p; break;    // 16*19*19*208
      default: break;
    }
  }
  char* ws = (char*)d_ws;
  float* sel_score = (float*)(ws + WS_SELS);
  int* sel_idx = (int*)(ws + WS_SELI);
  int* cnt = (int*)(ws + WS_CNT);
  float* ws_box = (float*)(ws + WS_BOX);
  u64* ws_mask = (u64*)(ws + WS_MASK);
  int* ws_src = (int*)(ws + WS_SRC);

  topk_kernel<<<dim3(48), dim3(TK_T), 0, stream>>>(pred[0], pred[1], pred[2], sel_score, sel_idx, cnt);
  rank_kernel<<<dim3(16), dim3(1024), 0, stream>>>(pred[0], pred[1], pred[2], sel_score, sel_idx, cnt, ws_box);
  mask_kernel<<<dim3(15, 16), dim3(256), 0, stream>>>(ws_box, cnt, ws_mask);
  scan_kernel<<<dim3(16), dim3(256), 0, stream>>>(ws_mask, cnt, ws_src);
  out_kernel<<<dim3(2000), dim3(256), 0, stream>>>(emb[0], emb[1], emb[2], ws_box, ws_src, sel_idx, (float*)d_out);
}

// Round 3
// 270.343 us; speedup vs baseline: 1.5071x; 1.0234x over previous
//
#include <hip/hip_runtime.h>

typedef unsigned long long u64;
typedef unsigned int u32;

#define KLVL 300
#define NPROP 900
#define MAXPROP 500
#define DDIM 213
#define EDIM 208

// anchors_px / stride (all exact in binary: /8,/16,/32)
__constant__ float c_anc[3][4][2] = {
  {{1.0f, 3.0f}, {1.375f, 4.25f}, {2.0f, 6.0f}, {2.875f, 8.5f}},
  {{2.0f, 6.0f}, {2.8125f, 8.4375f}, {4.0f, 12.0f}, {5.625f, 16.9375f}},
  {{4.0f, 12.0f}, {5.625f, 16.875f}, {8.0f, 20.0f}, {16.0f, 20.0f}},
};
__constant__ float c_scale[3] = { (float)(8.0 / 608.0), (float)(16.0 / 608.0), (float)(32.0 / 608.0) };

__device__ __forceinline__ int level_H(int lvl) { return (lvl == 0) ? 76 : ((lvl == 1) ? 38 : 19); }

// ---------------- workspace layout (bytes) ----------------
// scores region (dead after select_kernel) is overlapped by the IoU mask.
#define SB_STRIDE 30336           // per-image score stride (elems); 23104+5776+1444=30324
#define WS_SCORES 0               // 16*30336 f32 = 1,941,504 B
#define WS_MASK   0               // 16*904*15 u64 = 1,735,680 B  (aliases scores)
#define MASK_IMG (904*15)
#define WS_SELS (1941504)         // 16*900 f32
#define WS_SELI (WS_SELS + 57600) // 16*900 i32
#define WS_CNT  (WS_SELI + 57600) // 48 i32 (+pad)
#define WS_BOX  (WS_CNT + 256)    // 16 * 7 * 928 f32
#define BOX_STRIDE 928
#define BOX_IMG (7*928)
#define WS_SRC  (WS_BOX + 415744) // 16*500 i32

// ---------------------------------------------------------------------------
// Kernel 1: conf scores for ALL anchors, massively parallel, dense output
// grid = 16*120 = 1920 (91 lvl0 + 23 lvl1 + 6 lvl2 blocks per image), block = 256
// ---------------------------------------------------------------------------
__global__ __launch_bounds__(256) void score_kernel(
    const float* __restrict__ pred0, const float* __restrict__ pred1, const float* __restrict__ pred2,
    float* __restrict__ ws_scores)
{
  const int blk = blockIdx.x;
  const int b = blk / 120;
  const int r = blk % 120;
  int lvl, rb, N, off;
  const float* pred;
  if (r < 91)       { lvl = 0; rb = r;       N = 23104; off = 0;     pred = pred0; }
  else if (r < 114) { lvl = 1; rb = r - 91;  N = 5776;  off = 23104; pred = pred1; }
  else              { lvl = 2; rb = r - 114; N = 1444;  off = 28880; pred = pred2; }
  (void)lvl;
  const int n = rb * 256 + (int)threadIdx.x;
  if (n >= N) return;
  const float* pb = pred + (size_t)b * N * 6;
  float2 l = *reinterpret_cast<const float2*>(pb + (size_t)n * 6 + 4);
  float m = fmaxf(l.x, l.y);
  float e0 = expf(l.x - m), e1 = expf(l.y - m);
  float s = e1 / (e0 + e1);
  ws_scores[(size_t)b * SB_STRIDE + off + n] = (s > 0.5f) ? s : 0.0f;
}

// ---------------------------------------------------------------------------
// Kernel 2: per-(image,level) exact top-300 (sorted) from dense scores
// grid = 48 (b*3+lvl), block = 1024
// ---------------------------------------------------------------------------
#define TK_T 1024
__global__ __launch_bounds__(TK_T) void select_kernel(
    const float* __restrict__ ws_scores,
    float* __restrict__ sel_score, int* __restrict__ sel_idx, int* __restrict__ cnt)
{
  __shared__ float s_sc[23104];
  __shared__ u32 s_hist[4096];
  __shared__ u32 s_wt[16];
  __shared__ u64 s_wt64[16];
  __shared__ u32 s_sel[4];
  __shared__ float s_selS[KLVL];
  __shared__ int   s_selI[KLVL];

  const int lvl = blockIdx.x % 3;
  const int b = blockIdx.x / 3;
  const int t = threadIdx.x;
  const int lane = t & 63, wid = t >> 6;
  const int H = level_H(lvl);
  const int N = 4 * H * H;
  const int off = (lvl == 0) ? 0 : ((lvl == 1) ? 23104 : 28880);
  const float* gs = ws_scores + (size_t)b * SB_STRIDE + off;

  if (t == 0) s_sel[2] = 0;
  u32 nploc = 0;
  for (int n = t; n < N; n += TK_T) {
    float sm = gs[n];
    s_sc[n] = sm;
    nploc += (sm > 0.0f) ? 1u : 0u;
  }
  __syncthreads();
  if (nploc) atomicAdd(&s_sel[2], nploc);
  __syncthreads();
  const u32 Npos = s_sel[2];
  const bool take_all = (Npos <= (u32)KLVL);
  u32 K = KLVL;
  u32 prefHi = 0, Tkey = 0;

  if (!take_all) {
    // 2-pass radix select over key = float_bits - 0x3F000000 (conf in (0.5, 1])
    for (int pass = 0; pass < 2; ++pass) {
      for (int i = t; i < 4096; i += TK_T) s_hist[i] = 0;
      __syncthreads();
      for (int n = t; n < N; n += TK_T) {
        float v = s_sc[n];
        if (v <= 0.0f) continue;
        u32 key = __float_as_uint(v) - 0x3F000000u;
        if (pass == 0) atomicAdd(&s_hist[key >> 12], 1u);
        else if ((key >> 12) == prefHi) atomicAdd(&s_hist[key & 0xFFFu], 1u);
      }
      __syncthreads();
      // thread t owns 4 buckets from the top: 4095-4t, ...
      const int btop = 4095 - 4 * t;
      u32 h0 = s_hist[btop], h1 = s_hist[btop - 1], h2 = s_hist[btop - 2], h3 = s_hist[btop - 3];
      u32 partial = h0 + h1 + h2 + h3;
      u32 incl = partial;
      #pragma unroll
      for (int off2 = 1; off2 < 64; off2 <<= 1) { u32 v2 = __shfl_up(incl, (unsigned)off2, 64); if (lane >= off2) incl += v2; }
      if (lane == 63) s_wt[wid] = incl;
      __syncthreads();
      u32 above = 0;
      for (int w2 = 0; w2 < wid; ++w2) above += s_wt[w2];
      u32 running = above + incl - partial;
      if (h0 && running < K && K <= running + h0) { s_sel[0] = (u32)(btop);     s_sel[1] = K - running; }
      running += h0;
      if (h1 && running < K && K <= running + h1) { s_sel[0] = (u32)(btop - 1); s_sel[1] = K - running; }
      running += h1;
      if (h2 && running < K && K <= running + h2) { s_sel[0] = (u32)(btop - 2); s_sel[1] = K - running; }
      running += h2;
      if (h3 && running < K && K <= running + h3) { s_sel[0] = (u32)(btop - 3); s_sel[1] = K - running; }
      __syncthreads();
      if (pass == 0) prefHi = s_sel[0];
      else Tkey = (prefHi << 12) | s_sel[0];
      K = s_sel[1];
      __syncthreads();
    }
  }
  const u32 need_ties = take_all ? 0u : K;
  const u32 G = take_all ? Npos : ((u32)KLVL - need_ties);
  const u32 Tbits = Tkey + 0x3F000000u;

  // deterministic ordered compaction via packed (cg,ct) wave scans
  const int chunk = (N + TK_T - 1) / TK_T;
  const int lo = t * chunk;
  const int hi = (lo + chunk < N) ? (lo + chunk) : N;
  u32 cg = 0, ct = 0;
  for (int n = lo; n < hi; ++n) {
    float v = s_sc[n];
    if (v <= 0.0f) continue;
    u32 bits = __float_as_uint(v);
    if (take_all || bits > Tbits) cg++;
    else if (bits == Tbits) ct++;
  }
  u64 pc = ((u64)cg << 32) | (u64)ct;
  u64 incl64 = pc;
  #pragma unroll
  for (int off2 = 1; off2 < 64; off2 <<= 1) { u64 v2 = __shfl_up(incl64, (unsigned)off2, 64); if (lane >= off2) incl64 += v2; }
  if (lane == 63) s_wt64[wid] = incl64;
  __syncthreads();
  u64 ab = 0;
  for (int w2 = 0; w2 < wid; ++w2) ab += s_wt64[w2];
  u64 excl = ab + incl64 - pc;
  u32 g_pos = (u32)(excl >> 32);
  u32 t_pos = (u32)excl;
  for (int n = lo; n < hi; ++n) {
    float v = s_sc[n];
    if (v <= 0.0f) continue;
    u32 bits = __float_as_uint(v);
    if (take_all || bits > Tbits) {
      s_selS[g_pos] = v; s_selI[g_pos] = n; g_pos++;
    } else if (bits == Tbits) {
      if (t_pos < need_ties) { s_selS[G + t_pos] = v; s_selI[G + t_pos] = n; }
      t_pos++;
    }
  }
  __syncthreads();

  // rank the <=300 selected by (score desc, idx asc) -> write sorted (== lax.top_k order)
  const u32 total = take_all ? Npos : (u32)KLVL;
  float* out_s = sel_score + (size_t)b * NPROP + (size_t)lvl * KLVL;
  int* out_i = sel_idx + (size_t)b * NPROP + (size_t)lvl * KLVL;
  if ((u32)t < total) {
    float sv = s_selS[t]; int iv = s_selI[t];
    u32 r = 0;
    for (u32 j = 0; j < total; ++j) {
      float sj = s_selS[j]; int ij = s_selI[j];
      r += ((sj > sv) || (sj == sv && ij < iv)) ? 1u : 0u;
    }
    out_s[r] = sv; out_i[r] = iv;
  }
  for (u32 s2 = total + (u32)t; s2 < (u32)KLVL; s2 += TK_T) { out_s[s2] = 0.0f; out_i[s2] = 0; }
  if (t == 0) cnt[b * 3 + lvl] = (int)total;
}

// ---------------------------------------------------------------------------
// Kernel 3: global rank (3-way sorted merge via binary search) + box decode
// grid = 16, block = 1024
// ---------------------------------------------------------------------------
__global__ __launch_bounds__(1024) void rank_kernel(
    const float* __restrict__ pred0, const float* __restrict__ pred1, const float* __restrict__ pred2,
    const float* __restrict__ sel_score, const int* __restrict__ sel_idx, const int* __restrict__ cnt,
    float* __restrict__ ws_box)
{
  __shared__ float s_sc[NPROP];
  __shared__ int s_ix[NPROP];
  __shared__ int s_c[3];
  const int b = blockIdx.x, t = threadIdx.x;
  if (t < 3) s_c[t] = cnt[b * 3 + t];
  if (t < NPROP) { s_sc[t] = sel_score[(size_t)b * NPROP + t]; s_ix[t] = sel_idx[(size_t)b * NPROP + t]; }
  __syncthreads();
  if (t < NPROP) {
    int lvl = t / KLVL, pos = t - lvl * KLVL;
    if (pos < s_c[lvl]) {
      float sv = s_sc[t];
      u32 rank = (u32)pos;
      for (int ol = 0; ol < 3; ++ol) {
        if (ol == lvl) continue;
        int base = ol * KLVL, co = s_c[ol];
        int lo2 = 0, hi2 = co;
        if (ol < lvl) {  // earlier level: equal score ranks before me (count >=)
          while (lo2 < hi2) { int mid = (lo2 + hi2) >> 1; if (s_sc[base + mid] >= sv) lo2 = mid + 1; else hi2 = mid; }
        } else {         // later level: only strictly greater
          while (lo2 < hi2) { int mid = (lo2 + hi2) >> 1; if (s_sc[base + mid] > sv) lo2 = mid + 1; else hi2 = mid; }
        }
        rank += (u32)lo2;
      }
      int n = s_ix[t];
      int Hl = level_H(lvl), HWl = Hl * Hl;
      int a = n / HWl, rem = n - a * HWl, gy = rem / Hl, gx = rem - gy * Hl;
      const float* pred = (lvl == 0) ? pred0 : ((lvl == 1) ? pred1 : pred2);
      const float* p = pred + ((size_t)b * 4 * HWl + (size_t)n) * 6;
      float p0 = p[0], p1 = p[1], p2 = p[2], p3 = p[3];
      float aw = c_anc[lvl][a][0], ah = c_anc[lvl][a][1];
      float x = p0 * aw + (float)gx;
      float y = p1 * ah + (float)gy;
      float wv = expf(p2) * aw;
      float hv = expf(p3) * ah;
      float sc = c_scale[lvl];
      float x1 = fminf(fmaxf((x - 0.5f * wv) * sc, 0.0f), 1.0f);
      float y1 = fminf(fmaxf((y - 0.5f * hv) * sc, 0.0f), 1.0f);
      float x2 = fminf(fmaxf((x + 0.5f * wv) * sc, 0.0f), 1.0f);
      float y2 = fminf(fmaxf((y + 0.5f * hv) * sc, 0.0f), 1.0f);
      float* Bx = ws_box + (size_t)b * BOX_IMG;
      Bx[rank] = x1;
      Bx[BOX_STRIDE + rank] = y1;
      Bx[2 * BOX_STRIDE + rank] = x2;
      Bx[3 * BOX_STRIDE + rank] = y2;
      Bx[4 * BOX_STRIDE + rank] = (x2 - x1) * (y2 - y1);
      Bx[5 * BOX_STRIDE + rank] = sv;
      ((int*)(Bx + 6 * BOX_STRIDE))[rank] = t;   // slot
    }
  }
}

// ---------------------------------------------------------------------------
// Kernel 4: IoU suppression bitmask, spread over (word w, image b) blocks
// grid = (15, 16), block = 256
// ---------------------------------------------------------------------------
__global__ __launch_bounds__(256) void mask_kernel(
    const float* __restrict__ ws_box, const int* __restrict__ cnt, u64* __restrict__ ws_mask)
{
  const int w = blockIdx.x, b = blockIdx.y, t = threadIdx.x;
  const float* B = ws_box + (size_t)b * BOX_IMG;
  const float* X1 = B, * Y1 = B + BOX_STRIDE, * X2 = B + 2 * BOX_STRIDE,
             * Y2 = B + 3 * BOX_STRIDE, * AR = B + 4 * BOX_STRIDE;
  const int Np = cnt[b * 3] + cnt[b * 3 + 1] + cnt[b * 3 + 2];
  __shared__ float jx1[64], jy1[64], jx2[64], jy2[64], jar[64];
  if (t < 64) {
    int j = w * 64 + t;
    if (j < Np) { jx1[t] = X1[j]; jy1[t] = Y1[j]; jx2[t] = X2[j]; jy2[t] = Y2[j]; jar[t] = AR[j]; }
  }
  __syncthreads();
  u64* mk = ws_mask + (size_t)b * MASK_IMG;
  const int jlim = min(64, Np - w * 64);
  for (int i = t; i < Np; i += 256) {
    u64 bits = 0;
    if (i < w * 64 + 63 && jlim > 0) {
      float xi1 = X1[i], yi1 = Y1[i], xi2 = X2[i], yi2 = Y2[i], ai = AR[i];
      for (int jj = 0; jj < jlim; ++jj) {
        int j = w * 64 + jj;
        if (j > i) {
          float xx1 = fmaxf(xi1, jx1[jj]);
          float yy1 = fmaxf(yi1, jy1[jj]);
          float xx2 = fminf(xi2, jx2[jj]);
          float yy2 = fminf(yi2, jy2[jj]);
          float iw = fmaxf(xx2 - xx1, 0.0f);
          float ih = fmaxf(yy2 - yy1, 0.0f);
          float inter = iw * ih;
          float iou = inter / (ai + jar[jj] - inter + 1e-9f);
          if (iou > 0.45f) bits |= (1ull << jj);
        }
      }
    }
    mk[(size_t)i * 15 + w] = bits;
  }
}

// ---------------------------------------------------------------------------
// Kernel 5: serial greedy scan (readlane-based) + keep-rank -> src list
// grid = 16, block = 256 (scan runs on wave 0)
// ---------------------------------------------------------------------------
__global__ __launch_bounds__(256) void scan_kernel(
    const u64* __restrict__ ws_mask, const int* __restrict__ cnt, int* __restrict__ ws_src)
{
  __shared__ u64 sm[904 * 15];
  __shared__ u64 s_keep[15];
  __shared__ u32 s_pre[16];
  const int b = blockIdx.x, t = threadIdx.x;
  const int Np = cnt[b * 3] + cnt[b * 3 + 1] + cnt[b * 3 + 2];
  const u64* mk = ws_mask + (size_t)b * MASK_IMG;
  for (int i = t; i < Np * 15; i += 256) sm[i] = mk[i];
  __syncthreads();

  if (t < 64) {
    const int lane = t;
    const int lw = (lane < 15) ? lane : 0;
    u64 remv = 0;
    u64 r0 = sm[0 * 15 + lw], r1 = sm[1 * 15 + lw], r2 = sm[2 * 15 + lw], r3 = sm[3 * 15 + lw];
    const int Np4 = Np & ~3;
#define NMS_STEP(ii, rr) { \
      u32 bit_ = (u32)(remv >> ((ii) & 63)) & 1u; \
      u32 sup_ = (u32)__builtin_amdgcn_readlane((int)bit_, (ii) >> 6); \
      if (!sup_) remv |= (rr); }
    for (int i = 0; i < Np4; i += 4) {
      u64 n0 = sm[(size_t)(i + 4) * 15 + lw];
      u64 n1 = sm[(size_t)(i + 5) * 15 + lw];
      u64 n2 = sm[(size_t)(i + 6) * 15 + lw];
      u64 n3 = sm[(size_t)(i + 7) * 15 + lw];
      NMS_STEP(i, r0);
      NMS_STEP(i + 1, r1);
      NMS_STEP(i + 2, r2);
      NMS_STEP(i + 3, r3);
      r0 = n0; r1 = n1; r2 = n2; r3 = n3;
    }
    if (Np4 + 0 < Np) NMS_STEP(Np4 + 0, r0);
    if (Np4 + 1 < Np) NMS_STEP(Np4 + 1, r1);
    if (Np4 + 2 < Np) NMS_STEP(Np4 + 2, r2);
    if (Np4 + 3 < Np) NMS_STEP(Np4 + 3, r3);
#undef NMS_STEP
    if (lane < 15) {
      int base = lane << 6;
      u64 valid = 0;
      if (Np > base) {
        int r = Np - base;
        valid = (r >= 64) ? ~0ull : ((1ull << r) - 1ull);
      }
      s_keep[lane] = (~remv) & valid;
    }
  }
  __syncthreads();
  if (t == 0) {
    u32 run = 0;
    for (int w2 = 0; w2 < 15; ++w2) { s_pre[w2] = run; run += (u32)__popcll(s_keep[w2]); }
  }
  int* src = ws_src + b * MAXPROP;
  for (int r = t; r < MAXPROP; r += 256) src[r] = -1;
  __syncthreads();
  for (int i = t; i < Np; i += 256) {
    u64 kw = s_keep[i >> 6];
    if ((kw >> (i & 63)) & 1ull) {
      u32 rank = s_pre[i >> 6] + (u32)__popcll(kw & ((1ull << (i & 63)) - 1ull));
      if (rank < MAXPROP) src[rank] = i;
    }
  }
}

// ---------------------------------------------------------------------------
// Kernel 6: output rows — one wave per row, spread over 2000 blocks
// grid = 16*125, block = 256
// ---------------------------------------------------------------------------
__global__ __launch_bounds__(256) void out_kernel(
    const float* __restrict__ emb0, const float* __restrict__ emb1, const float* __restrict__ emb2,
    const float* __restrict__ ws_box, const int* __restrict__ ws_src, const int* __restrict__ sel_idx,
    float* __restrict__ out)
{
  const int blk = blockIdx.x;
  const int b = blk / 125;
  const int r = (blk % 125) * 4 + (threadIdx.x >> 6);
  const int lane = threadIdx.x & 63;
  float* orow = out + ((size_t)b * MAXPROP + r) * DDIM;
  const int i = ws_src[b * MAXPROP + r];
  if (i < 0) {
    for (int c = lane; c < DDIM; c += 64) orow[c] = 0.0f;
    return;
  }
  const float* B = ws_box + (size_t)b * BOX_IMG;
  float x1 = B[i], y1 = B[BOX_STRIDE + i], x2 = B[2 * BOX_STRIDE + i], y2 = B[3 * BOX_STRIDE + i];
  float score = B[5 * BOX_STRIDE + i];
  int slot = ((const int*)(B + 6 * BOX_STRIDE))[i];
  int n = sel_idx[(size_t)b * NPROP + slot];
  int lvl = slot / KLVL;
  int Hl = level_H(lvl), HWl = Hl * Hl;
  int a = n / HWl, rem = n - a * HWl, gy = rem / Hl, gx = rem - gy * Hl;
  (void)a;
  const float* emb = (lvl == 0) ? emb0 : ((lvl == 1) ? emb1 : emb2);
  const float* e = emb + ((size_t)(b * Hl + gy) * Hl + gx) * EDIM;
  float v0 = e[lane], v1 = e[lane + 64], v2 = e[lane + 128];
  float v3 = (lane < 16) ? e[lane + 192] : 0.0f;
  float ss = v0 * v0 + v1 * v1 + v2 * v2 + v3 * v3;
  for (int off = 32; off > 0; off >>= 1) ss += __shfl_xor(ss, off, 64);
  float rs = 1.0f / sqrtf(fmaxf(ss, 1e-12f));
  if (lane == 0) {
    orow[0] = x1; orow[1] = y1; orow[2] = x2; orow[3] = y2; orow[4] = score;
  }
  orow[5 + lane] = v0 * rs;
  orow[5 + 64 + lane] = v1 * rs;
  orow[5 + 128 + lane] = v2 * rs;
  if (lane < 16) orow[5 + 192 + lane] = v3 * rs;
}

// ---------------------------------------------------------------------------
extern "C" void kernel_launch(void* const* d_in, const int* in_sizes, int n_in,
                              void* d_out, int out_size, void* d_ws, size_t ws_size,
                              hipStream_t stream) {
  const float* pred[3] = {nullptr, nullptr, nullptr};
  const float* emb[3] = {nullptr, nullptr, nullptr};
  for (int i = 0; i < n_in; ++i) {
    const float* p = (const float*)d_in[i];
    switch (in_sizes[i]) {
      case 2217984:  pred[0] = p; break;   // 16*4*76*76*6
      case 554496:   pred[1] = p; break;   // 16*4*38*38*6
      case 138624:   pred[2] = p; break;   // 16*4*19*19*6
      case 19222528: emb[0] = p; break;    // 16*76*76*208
      case 4805632:  emb[1] = p; break;    // 16*38*38*208
      case 1201408:  emb[2] = p; break;    // 16*19*19*208
      default: break;
    }
  }
  char* ws = (char*)d_ws;
  float* ws_scores = (float*)(ws + WS_SCORES);
  u64* ws_mask = (u64*)(ws + WS_MASK);     // aliases scores region (scores dead after select)
  float* sel_score = (float*)(ws + WS_SELS);
  int* sel_idx = (int*)(ws + WS_SELI);
  int* cnt = (int*)(ws + WS_CNT);
  float* ws_box = (float*)(ws + WS_BOX);
  int* ws_src = (int*)(ws + WS_SRC);

  score_kernel<<<dim3(1920), dim3(256), 0, stream>>>(pred[0], pred[1], pred[2], ws_scores);
  select_kernel<<<dim3(48), dim3(TK_T), 0, stream>>>(ws_scores, sel_score, sel_idx, cnt);
  rank_kernel<<<dim3(16), dim3(1024), 0, stream>>>(pred[0], pred[1], pred[2], sel_score, sel_idx, cnt, ws_box);
  mask_kernel<<<dim3(15, 16), dim3(256), 0, stream>>>(ws_box, cnt, ws_mask);
  scan_kernel<<<dim3(16), dim3(256), 0, stream>>>(ws_mask, cnt, ws_src);
  out_kernel<<<dim3(2000), dim3(256), 0, stream>>>(emb[0], emb[1], emb[2], ws_box, ws_src, sel_idx, (float*)d_out);
}